// Round 5
// baseline (1011.769 us; speedup 1.0000x reference)
//
#include <hip/hip_runtime.h>
#include <hip/hip_bf16.h>

// Problem constants (fixed by setup_inputs)
#define BB_  64
#define TT_  512
#define FF_  1024
#define HH_  31
#define GG_  124   // 4*H
#define FUT_ 16
#define TTOT_ 528  // T + future
#define OUT_ROW_ ((size_t)TTOT_ * FF_)   // per-batch stride in output

// ---- workspace layout (float indices) ----
#define PRE1_OFF ((size_t)0)                              // [512][64][128]
#define H2A_OFF  (PRE1_OFF + (size_t)TT_*64*128)          // [528*64][32]
#define WT_OFF   (H2A_OFF  + (size_t)TTOT_*64*32)         // [31][1024]
#define MV_OFF   (WT_OFF   + 31*1024)                     // [124][32]

__device__ __forceinline__ float rdlane(float v, int k) {
    return __uint_as_float(__builtin_amdgcn_readlane(__float_as_uint(v), k));
}

#define REP16(M) M(0) M(1) M(2) M(3) M(4) M(5) M(6) M(7) \
                 M(8) M(9) M(10) M(11) M(12) M(13) M(14) M(15)

// ---------------- K0: transpose W_lin [1024][31] -> WT [31][1024] ----------------
__global__ void k0_prep(const float* __restrict__ Wlin, float* __restrict__ WT) {
    int i = blockIdx.x * 256 + threadIdx.x;   // 124*256 = 31744 = 1024*31 exactly
    int j = i / 31;
    int k = i - j * 31;
    WT[k * 1024 + j] = Wlin[i];
}

// ---------------- K0b: Mv[g][k] = sum_j Wih1[g][j]*Wlin[j][k]  (k=31 -> blin) ----------------
__global__ __launch_bounds__(64) void k0b_mv(
    const float* __restrict__ Wih1, const float* __restrict__ Wlin,
    const float* __restrict__ blin, float* __restrict__ Mv)
{
    int i = blockIdx.x * 64 + threadIdx.x;   // 62*64 = 3968 = 124*32
    int g = i >> 5, k = i & 31;
    const float* wr = Wih1 + (size_t)g * FF_;
    float acc = 0.0f;
    if (k < 31) {
#pragma unroll 8
        for (int j = 0; j < FF_; j++) acc += wr[j] * Wlin[j * 31 + k];
    } else {
#pragma unroll 8
        for (int j = 0; j < FF_; j++) acc += wr[j] * blin[j];
    }
    Mv[i] = acc;
}

// ---------------- K1: pregate GEMM: pre1[t][b][g] = x[b][t] . Wih1[g] + b1 ----------------
__global__ __launch_bounds__(256) void k1_pregate(
    const float* __restrict__ X,      // [B][T][F] fp32
    const float* __restrict__ Wih1,   // [G][F] fp32
    const float* __restrict__ bih1,
    const float* __restrict__ bhh1,
    float* __restrict__ pre1)         // [T][B][128]
{
    __shared__ __align__(16) float xs[32][64];    // [k][row]
    __shared__ __align__(16) float ws[32][128];   // [k][col]
    const int tid  = threadIdx.x;
    const int t    = blockIdx.x;
    const int tcol = tid & 31, trow = tid >> 5;
    const int c0 = tcol * 4, r0 = trow * 8;

    float4 acc[8];
#pragma unroll
    for (int r = 0; r < 8; r++) acc[r] = make_float4(0.f, 0.f, 0.f, 0.f);

    for (int kc = 0; kc < 32; ++kc) {
        const int k0 = kc * 32;
#pragma unroll
        for (int p = 0; p < 2; p++) {
            int i = tid + p * 256;
            int r = i >> 3, f = i & 7;
            float4 v = *(const float4*)(X + (size_t)r * TT_ * FF_ + (size_t)t * FF_ + k0 + f * 4);
            xs[f * 4 + 0][r] = v.x; xs[f * 4 + 1][r] = v.y;
            xs[f * 4 + 2][r] = v.z; xs[f * 4 + 3][r] = v.w;
        }
#pragma unroll
        for (int p = 0; p < 4; p++) {
            int i = tid + p * 256;
            int g = i >> 3, f = i & 7;
            float4 v = make_float4(0.f, 0.f, 0.f, 0.f);
            if (g < GG_) v = *(const float4*)(Wih1 + (size_t)g * FF_ + k0 + f * 4);
            ws[f * 4 + 0][g] = v.x; ws[f * 4 + 1][g] = v.y;
            ws[f * 4 + 2][g] = v.z; ws[f * 4 + 3][g] = v.w;
        }
        __syncthreads();
#pragma unroll
        for (int k = 0; k < 32; k++) {
            float4 wv = *(const float4*)&ws[k][c0];
            float4 xa = *(const float4*)&xs[k][r0];
            float4 xb = *(const float4*)&xs[k][r0 + 4];
            float rx[8] = {xa.x, xa.y, xa.z, xa.w, xb.x, xb.y, xb.z, xb.w};
#pragma unroll
            for (int r = 0; r < 8; r++) {
                acc[r].x += rx[r] * wv.x; acc[r].y += rx[r] * wv.y;
                acc[r].z += rx[r] * wv.z; acc[r].w += rx[r] * wv.w;
            }
        }
        __syncthreads();
    }
    float bias[4];
#pragma unroll
    for (int cc = 0; cc < 4; cc++) {
        int c = c0 + cc;
        bias[cc] = (c < GG_) ? (bih1[c] + bhh1[c]) : 0.0f;
    }
#pragma unroll
    for (int r = 0; r < 8; r++) {
        int m = t * 64 + r0 + r;
        float4 o = acc[r];
        o.x += bias[0]; o.y += bias[1]; o.z += bias[2]; o.w += bias[3];
        *(float4*)(pre1 + (size_t)m * 128 + c0) = o;
    }
}

// ---------------- K2: sequential recurrence, SPLIT-K over wave pairs ----------------
// 256 threads = 4 waves. Waves 0/1: gates 0..123, k-half 0 (k=0..15);
// waves 2/3: same gates, k-half 1 (k=16..30, zero-padded 16th term).
// Per-lane weight footprint: 48 floats (fits the ~72-VGPR allocation the
// compiler demonstrably produces; rounds 2-4 proved it will NOT hold 93).
// k-range is wave-uniform -> readlane uses uniform SGPR lane-select, no
// divergence. Half-partials are combined by state-owner lanes (j=(L&63)<31,
// replicated in ALL 4 waves so readlane broadcast stays within-wave) via a
// double-buffered LDS partial array; ONE barrier per main step.
// hv2 on lane j==31 is pinned to 1.0 so the future-loop's Mv column 31
// (the v vector) folds into the uniform dot as m_15 * h2[31].
// NOTE: splitting a serial accumulation at k=16 changes FP association;
// output is no longer bit-identical to rounds 0-4 (absmax may move off
// 0.001953125 but must stay ~2e-3 magnitude).
__global__ __launch_bounds__(256, 1) void k2_recur(
    const float* __restrict__ pre1,   // [T][B][128]  (bias already folded in)
    const float* __restrict__ Whh1,   // [G][H]
    const float* __restrict__ Wih2,   // [G][H]
    const float* __restrict__ Whh2,   // [G][H]
    const float* __restrict__ bih1, const float* __restrict__ bhh1,
    const float* __restrict__ bih2, const float* __restrict__ bhh2,
    const float* __restrict__ Mv,     // [124][32]  (M | v)
    float* __restrict__ h2a)          // [528*64][32]
{
    __shared__ float pbuf[2][2][2][128];  // [t-parity][0=L1pre,1=L2pre][half][gate-slot]
    const int L    = threadIdx.x;         // 0..255
    const int bb   = blockIdx.x;
    const int wid  = L >> 6;              // wave 0..3
    const int j    = L & 63;              // lane in wave
    const int half = wid >> 1;            // k-half: 0 -> k=0..15, 1 -> k=16..30(+pad)
    const int gl   = (wid & 1) * 64 + j;  // gate slot 0..127 (124..127 dummy)
    const int g    = (gl < GG_) ? gl : (GG_ - 1);
    const bool own = (j < HH_);           // state-owner lane (all 4 waves)
    const int KLO  = half * 16;

    // 48 weight floats per lane, named scalars; zero-pad k=31 slot for half 1
#define WLOAD(i) float w1_##i  = (KLO + i < HH_) ? Whh1[g * 31 + KLO + i] : 0.0f; \
                 float wi2_##i = (KLO + i < HH_) ? Wih2[g * 31 + KLO + i] : 0.0f; \
                 float wh2_##i = (KLO + i < HH_) ? Whh2[g * 31 + KLO + i] : 0.0f;
    REP16(WLOAD)
#undef WLOAD
#define WPIN(i) asm("" : "+v"(w1_##i), "+v"(wi2_##i), "+v"(wh2_##i));
    REP16(WPIN)
#undef WPIN

    // per-gate biases folded into half-0 partials only
    const float b2c = (half == 0) ? (bih2[g] + bhh2[g]) : 0.0f;
    const float b1c = (half == 0) ? (bih1[g] + bhh1[g]) : 0.0f;

    float hv1 = 0.0f, cv1 = 0.0f, cv2 = 0.0f;
    float hv2 = (j == 31) ? 1.0f : 0.0f;   // lane 31 = constant 1.0 (v-column trick)

    // pregate stream: only half-0 waves carry it
    float cur0 = 0.0f, pnxt = 0.0f;
    if (half == 0) {
        cur0 = pre1[(size_t)bb * 128 + gl];
        pnxt = pre1[((size_t)64 + bb) * 128 + gl];   // p(1)
    }

    // ---- prologue: L1(0) gates; hv1==0 so partial is just cur0 (half0) / 0 (half1)
    pbuf[1][0][half][gl] = (half == 0) ? cur0 : 0.0f;
    __syncthreads();
    if (own) {
        float ai = pbuf[1][0][0][j]      + pbuf[1][0][1][j];
        float af = pbuf[1][0][0][j + 31] + pbuf[1][0][1][j + 31];
        float ag = pbuf[1][0][0][j + 62] + pbuf[1][0][1][j + 62];
        float ao = pbuf[1][0][0][j + 93] + pbuf[1][0][1][j + 93];
        float i1 = 1.0f / (1.0f + __expf(-ai));
        float f1 = 1.0f / (1.0f + __expf(-af));
        float s1 = 1.0f / (1.0f + __expf(-2.0f * ag));
        float g1 = 2.0f * s1 - 1.0f;
        float o1 = 1.0f / (1.0f + __expf(-ao));
        cv1 = f1 * cv1 + i1 * g1;
        float e1 = __expf(-2.0f * cv1);
        hv1 = o1 * (2.0f / (1.0f + e1) - 1.0f);   // h1(0)
    }

    // ---- main merged loop: iteration t computes L2(t) + L1(t+1), t = 0..510 ----
    for (int t = 0; t < TT_ - 1; t++) {
        const int par = t & 1;
        const float cur = pnxt;          // p(t+1)
        float pld = 0.0f;
        if (half == 0 && t + 2 < TT_) pld = pre1[((size_t)(t + 2) * 64 + bb) * 128 + gl];

        float pb = b2c;                           // L2(t) half-partial
        float pa = (half == 0) ? cur : 0.0f;      // L1(t+1) half-partial
#define DOTM(i) { float h1k = rdlane(hv1, KLO + i); float h2k = rdlane(hv2, KLO + i); \
                  pb += wi2_##i * h1k + wh2_##i * h2k; \
                  pa += w1_##i * h1k; }
        REP16(DOTM)
#undef DOTM
        pbuf[par][1][half][gl] = pb;
        pbuf[par][0][half][gl] = pa;
        __syncthreads();
        if (own) {
            // layer-2 state update -> h2(t)
            float bi = pbuf[par][1][0][j]      + pbuf[par][1][1][j];
            float bf = pbuf[par][1][0][j + 31] + pbuf[par][1][1][j + 31];
            float bg = pbuf[par][1][0][j + 62] + pbuf[par][1][1][j + 62];
            float bo = pbuf[par][1][0][j + 93] + pbuf[par][1][1][j + 93];
            float ig = 1.0f / (1.0f + __expf(-bi));
            float fg = 1.0f / (1.0f + __expf(-bf));
            float sg = 1.0f / (1.0f + __expf(-2.0f * bg));
            float gg = 2.0f * sg - 1.0f;
            float og = 1.0f / (1.0f + __expf(-bo));
            cv2 = fg * cv2 + ig * gg;
            float e2 = __expf(-2.0f * cv2);
            hv2 = og * (2.0f / (1.0f + e2) - 1.0f);
            // layer-1 state update -> h1(t+1)
            float ai = pbuf[par][0][0][j]      + pbuf[par][0][1][j];
            float af = pbuf[par][0][0][j + 31] + pbuf[par][0][1][j + 31];
            float ag = pbuf[par][0][0][j + 62] + pbuf[par][0][1][j + 62];
            float ao = pbuf[par][0][0][j + 93] + pbuf[par][0][1][j + 93];
            float i1 = 1.0f / (1.0f + __expf(-ai));
            float f1 = 1.0f / (1.0f + __expf(-af));
            float s1 = 1.0f / (1.0f + __expf(-2.0f * ag));
            float g1 = 2.0f * s1 - 1.0f;
            float o1 = 1.0f / (1.0f + __expf(-ao));
            cv1 = f1 * cv1 + i1 * g1;
            float e1 = __expf(-2.0f * cv1);
            hv1 = o1 * (2.0f / (1.0f + e1) - 1.0f);
        }
        if (L < HH_) h2a[((size_t)t * 64 + bb) * 32 + L] = hv2;
        pnxt = pld;
    }

    // ---- tail: L2(511) only (par = 1) ----
    {
        float pb = b2c;
#define DOTT(i) { float h1k = rdlane(hv1, KLO + i); float h2k = rdlane(hv2, KLO + i); \
                  pb += wi2_##i * h1k + wh2_##i * h2k; }
        REP16(DOTT)
#undef DOTT
        pbuf[1][1][half][gl] = pb;
    }
    __syncthreads();
    if (own) {
        float bi = pbuf[1][1][0][j]      + pbuf[1][1][1][j];
        float bf = pbuf[1][1][0][j + 31] + pbuf[1][1][1][j + 31];
        float bg = pbuf[1][1][0][j + 62] + pbuf[1][1][1][j + 62];
        float bo = pbuf[1][1][0][j + 93] + pbuf[1][1][1][j + 93];
        float ig = 1.0f / (1.0f + __expf(-bi));
        float fg = 1.0f / (1.0f + __expf(-bf));
        float sg = 1.0f / (1.0f + __expf(-2.0f * bg));
        float gg = 2.0f * sg - 1.0f;
        float og = 1.0f / (1.0f + __expf(-bo));
        cv2 = fg * cv2 + ig * gg;
        float e2 = __expf(-2.0f * cv2);
        hv2 = og * (2.0f / (1.0f + e2) - 1.0f);   // h2(511)
    }
    if (L < HH_) h2a[((size_t)(TT_ - 1) * 64 + bb) * 32 + L] = hv2;

    // ---- autoregressive future: pregate = M*h2 + v + b1 (v via h2[31]==1) ----
#define MLOAD(i) float m_##i = Mv[g * 32 + KLO + i];
    REP16(MLOAD)
#undef MLOAD
#define MPIN(i) asm("" : "+v"(m_##i));
    REP16(MPIN)
#undef MPIN

    for (int s = 0; s < FUT_; s++) {
        // phase A: L1 pregate partials
        float pa = b1c;
#define DF1(i) { float h2k = rdlane(hv2, KLO + i); pa += m_##i * h2k; }
        REP16(DF1)
#undef DF1
#define DF2(i) { float h1k = rdlane(hv1, KLO + i); pa += w1_##i * h1k; }
        REP16(DF2)
#undef DF2
        pbuf[0][0][half][gl] = pa;
        __syncthreads();
        if (own) {
            float ai = pbuf[0][0][0][j]      + pbuf[0][0][1][j];
            float af = pbuf[0][0][0][j + 31] + pbuf[0][0][1][j + 31];
            float ag = pbuf[0][0][0][j + 62] + pbuf[0][0][1][j + 62];
            float ao = pbuf[0][0][0][j + 93] + pbuf[0][0][1][j + 93];
            float i1 = 1.0f / (1.0f + __expf(-ai));
            float f1 = 1.0f / (1.0f + __expf(-af));
            float s1 = 1.0f / (1.0f + __expf(-2.0f * ag));
            float g1 = 2.0f * s1 - 1.0f;
            float o1 = 1.0f / (1.0f + __expf(-ao));
            cv1 = f1 * cv1 + i1 * g1;
            float e1 = __expf(-2.0f * cv1);
            hv1 = o1 * (2.0f / (1.0f + e1) - 1.0f);
        }
        // phase B: L2 gates
        float pb = b2c;
#define DF3(i) { float h1k = rdlane(hv1, KLO + i); float h2k = rdlane(hv2, KLO + i); \
                 pb += wi2_##i * h1k + wh2_##i * h2k; }
        REP16(DF3)
#undef DF3
        pbuf[0][1][half][gl] = pb;
        __syncthreads();
        if (own) {
            float bi = pbuf[0][1][0][j]      + pbuf[0][1][1][j];
            float bf = pbuf[0][1][0][j + 31] + pbuf[0][1][1][j + 31];
            float bg = pbuf[0][1][0][j + 62] + pbuf[0][1][1][j + 62];
            float bo = pbuf[0][1][0][j + 93] + pbuf[0][1][1][j + 93];
            float ig = 1.0f / (1.0f + __expf(-bi));
            float fg = 1.0f / (1.0f + __expf(-bf));
            float sg = 1.0f / (1.0f + __expf(-2.0f * bg));
            float gg = 2.0f * sg - 1.0f;
            float og = 1.0f / (1.0f + __expf(-bo));
            cv2 = fg * cv2 + ig * gg;
            float e2 = __expf(-2.0f * cv2);
            hv2 = og * (2.0f / (1.0f + e2) - 1.0f);
        }
        if (L < HH_) h2a[((size_t)(TT_ + s) * 64 + bb) * 32 + L] = hv2;
    }
}

// ---------------- K3: output linear for ALL 528 steps: out[b][t][:] = h2 . WT + b ----------------
__global__ __launch_bounds__(256) void k3_outlin(
    const float* __restrict__ h2a,   // [528*64][32]
    const float* __restrict__ WT,    // [31][1024]
    const float* __restrict__ blin,  // [1024]
    float* __restrict__ out)         // [B][528][1024] fp32
{
    __shared__ __align__(16) float hl[16][32];
    const int tid = threadIdx.x;
    const int m0  = blockIdx.x * 16;
#pragma unroll
    for (int p = 0; p < 2; p++) {
        int i = tid + p * 256;
        int r = i >> 5, k = i & 31;
        hl[r][k] = h2a[(size_t)(m0 + r) * 32 + k];
    }
    __syncthreads();
    const int c0 = tid * 4;
    float4 bl = *(const float4*)(blin + c0);
    float4 acc[16];
#pragma unroll
    for (int r = 0; r < 16; r++) acc[r] = bl;
    for (int k = 0; k < 31; k++) {
        float4 wv = *(const float4*)(WT + k * 1024 + c0);
#pragma unroll
        for (int r = 0; r < 16; r++) {
            float h = hl[r][k];
            acc[r].x += h * wv.x; acc[r].y += h * wv.y;
            acc[r].z += h * wv.z; acc[r].w += h * wv.w;
        }
    }
    const int t  = m0 >> 6;
    const int b0 = m0 & 63;
#pragma unroll
    for (int r = 0; r < 16; r++) {
        int b = b0 + r;
        *(float4*)(out + (size_t)b * OUT_ROW_ + (size_t)t * FF_ + c0) = acc[r];
    }
}

extern "C" void kernel_launch(void* const* d_in, const int* in_sizes, int n_in,
                              void* d_out, int out_size, void* d_ws, size_t ws_size,
                              hipStream_t stream) {
    (void)in_sizes; (void)n_in; (void)out_size; (void)ws_size;
    const float* X    = (const float*)d_in[0];
    const float* Wih1 = (const float*)d_in[1];
    const float* Whh1 = (const float*)d_in[2];
    const float* bih1 = (const float*)d_in[3];
    const float* bhh1 = (const float*)d_in[4];
    const float* Wih2 = (const float*)d_in[5];
    const float* Whh2 = (const float*)d_in[6];
    const float* bih2 = (const float*)d_in[7];
    const float* bhh2 = (const float*)d_in[8];
    const float* Wlin = (const float*)d_in[9];
    const float* blin = (const float*)d_in[10];
    // d_in[11] = future = 16 (constant for this problem)

    float* ws   = (float*)d_ws;
    float* pre1 = ws + PRE1_OFF;
    float* h2a  = ws + H2A_OFF;
    float* WT   = ws + WT_OFF;
    float* Mv   = ws + MV_OFF;
    float* out  = (float*)d_out;

    hipLaunchKernelGGL(k0_prep,    dim3(124),  dim3(256), 0, stream, Wlin, WT);
    hipLaunchKernelGGL(k0b_mv,     dim3(62),   dim3(64),  0, stream, Wih1, Wlin, blin, Mv);
    hipLaunchKernelGGL(k1_pregate, dim3(TT_),  dim3(256), 0, stream, X, Wih1, bih1, bhh1, pre1);
    hipLaunchKernelGGL(k2_recur,   dim3(BB_),  dim3(256), 0, stream, pre1, Whh1, Wih2, Whh2,
                       bih1, bhh1, bih2, bhh2, Mv, h2a);
    hipLaunchKernelGGL(k3_outlin,  dim3(TTOT_*4), dim3(256), 0, stream, h2a, WT, blin, out);
}

// Round 6
// 809.864 us; speedup vs baseline: 1.2493x; 1.2493x over previous
//
#include <hip/hip_runtime.h>
#include <hip/hip_bf16.h>

// Problem constants (fixed by setup_inputs)
#define BB_  64
#define TT_  512
#define FF_  1024
#define HH_  31
#define GG_  124   // 4*H
#define FUT_ 16
#define TTOT_ 528  // T + future
#define OUT_ROW_ ((size_t)TTOT_ * FF_)   // per-batch stride in output

// ---- workspace layout (float indices) ----
#define PRE1_OFF ((size_t)0)                              // [512][64][128]
#define H2A_OFF  (PRE1_OFF + (size_t)TT_*64*128)          // [528*64][32]
#define WT_OFF   (H2A_OFF  + (size_t)TTOT_*64*32)         // [31][1024]
#define MV_OFF   (WT_OFF   + 31*1024)                     // [124][32]

__device__ __forceinline__ float rdlane(float v, int k) {
    return __uint_as_float(__builtin_amdgcn_readlane(__float_as_uint(v), k));
}

// repeat macros
#define REP31(M) M(0) M(1) M(2) M(3) M(4) M(5) M(6) M(7) M(8) M(9) \
                 M(10) M(11) M(12) M(13) M(14) M(15) M(16) M(17) M(18) M(19) \
                 M(20) M(21) M(22) M(23) M(24) M(25) M(26) M(27) M(28) M(29) M(30)
#define REP16E(M) M(0) M(2) M(4) M(6) M(8) M(10) M(12) M(14) \
                  M(16) M(18) M(20) M(22) M(24) M(26) M(28) M(30)
#define REP15O(M) M(1) M(3) M(5) M(7) M(9) M(11) M(13) M(15) \
                  M(17) M(19) M(21) M(23) M(25) M(27) M(29)

// ---------------- K0: transpose W_lin [1024][31] -> WT [31][1024] ----------------
__global__ void k0_prep(const float* __restrict__ Wlin, float* __restrict__ WT) {
    int i = blockIdx.x * 256 + threadIdx.x;   // 124*256 = 31744 = 1024*31 exactly
    int j = i / 31;
    int k = i - j * 31;
    WT[k * 1024 + j] = Wlin[i];
}

// ---------------- K0b: Mv[g][k] = sum_j Wih1[g][j]*Wlin[j][k]  (k=31 -> blin) ----------------
__global__ __launch_bounds__(64) void k0b_mv(
    const float* __restrict__ Wih1, const float* __restrict__ Wlin,
    const float* __restrict__ blin, float* __restrict__ Mv)
{
    int i = blockIdx.x * 64 + threadIdx.x;   // 62*64 = 3968 = 124*32
    int g = i >> 5, k = i & 31;
    const float* wr = Wih1 + (size_t)g * FF_;
    float acc = 0.0f;
    if (k < 31) {
#pragma unroll 8
        for (int j = 0; j < FF_; j++) acc += wr[j] * Wlin[j * 31 + k];
    } else {
#pragma unroll 8
        for (int j = 0; j < FF_; j++) acc += wr[j] * blin[j];
    }
    Mv[i] = acc;
}

// ---------------- K1: pregate GEMM: pre1[t][b][g] = x[b][t] . Wih1[g] + b1 ----------------
__global__ __launch_bounds__(256) void k1_pregate(
    const float* __restrict__ X,      // [B][T][F] fp32
    const float* __restrict__ Wih1,   // [G][F] fp32
    const float* __restrict__ bih1,
    const float* __restrict__ bhh1,
    float* __restrict__ pre1)         // [T][B][128]
{
    __shared__ __align__(16) float xs[32][64];    // [k][row]
    __shared__ __align__(16) float ws[32][128];   // [k][col]
    const int tid  = threadIdx.x;
    const int t    = blockIdx.x;
    const int tcol = tid & 31, trow = tid >> 5;
    const int c0 = tcol * 4, r0 = trow * 8;

    float4 acc[8];
#pragma unroll
    for (int r = 0; r < 8; r++) acc[r] = make_float4(0.f, 0.f, 0.f, 0.f);

    for (int kc = 0; kc < 32; ++kc) {
        const int k0 = kc * 32;
#pragma unroll
        for (int p = 0; p < 2; p++) {
            int i = tid + p * 256;
            int r = i >> 3, f = i & 7;
            float4 v = *(const float4*)(X + (size_t)r * TT_ * FF_ + (size_t)t * FF_ + k0 + f * 4);
            xs[f * 4 + 0][r] = v.x; xs[f * 4 + 1][r] = v.y;
            xs[f * 4 + 2][r] = v.z; xs[f * 4 + 3][r] = v.w;
        }
#pragma unroll
        for (int p = 0; p < 4; p++) {
            int i = tid + p * 256;
            int g = i >> 3, f = i & 7;
            float4 v = make_float4(0.f, 0.f, 0.f, 0.f);
            if (g < GG_) v = *(const float4*)(Wih1 + (size_t)g * FF_ + k0 + f * 4);
            ws[f * 4 + 0][g] = v.x; ws[f * 4 + 1][g] = v.y;
            ws[f * 4 + 2][g] = v.z; ws[f * 4 + 3][g] = v.w;
        }
        __syncthreads();
#pragma unroll
        for (int k = 0; k < 32; k++) {
            float4 wv = *(const float4*)&ws[k][c0];
            float4 xa = *(const float4*)&xs[k][r0];
            float4 xb = *(const float4*)&xs[k][r0 + 4];
            float rx[8] = {xa.x, xa.y, xa.z, xa.w, xb.x, xb.y, xb.z, xb.w};
#pragma unroll
            for (int r = 0; r < 8; r++) {
                acc[r].x += rx[r] * wv.x; acc[r].y += rx[r] * wv.y;
                acc[r].z += rx[r] * wv.z; acc[r].w += rx[r] * wv.w;
            }
        }
        __syncthreads();
    }
    float bias[4];
#pragma unroll
    for (int cc = 0; cc < 4; cc++) {
        int c = c0 + cc;
        bias[cc] = (c < GG_) ? (bih1[c] + bhh1[c]) : 0.0f;
    }
#pragma unroll
    for (int r = 0; r < 8; r++) {
        int m = t * 64 + r0 + r;
        float4 o = acc[r];
        o.x += bias[0]; o.y += bias[1]; o.z += bias[2]; o.w += bias[3];
        *(float4*)(pre1 + (size_t)m * 128 + c0) = o;
    }
}

// ---------------- K2: sequential recurrence, merged-phase + split-ownership ----------------
// 128 threads, 1 gate per lane (gate L; lanes 124-127 dummy). R2/R4 structure
// (merged L2(t)+L1(t+1), one barrier/step) with two cycle-level changes driven
// by the R5 counter analysis (active SIMDs are ~50-60% issue-busy -> the loop
// is near its issue/latency floor; optimize cycles, not allocation):
//  1. SPLIT STATE OWNERSHIP: lanes 0..30 of each wave own layer-2 state
//     (cv2/hv2), lanes 32..62 own layer-1 state (cv1/hv1), in ONE unified
//     branchless update per lane. Halves the owner-region latency (was: 31/64
//     lanes serially doing both updates). rdlane(hv,k)=h2[k],
//     rdlane(hv,32+k)=h1[k].
//  2. SPLIT ACCUMULATOR CHAINS: b-dot as 4 independent chains (wi2/wh2 x
//     even/odd k), a-dot as 2 -> dependent-FMA depth 62 -> 16, latency hidden
//     under issue. (FP association changes; R5 showed absmax is insensitive.)
//  3. pre1 prefetch deepened to 2 steps.
__global__ __attribute__((amdgpu_flat_work_group_size(128, 128), amdgpu_waves_per_eu(1)))
void k2_recur(
    const float* __restrict__ pre1,   // [T][B][128]  (bias already folded in)
    const float* __restrict__ Whh1,   // [G][H]
    const float* __restrict__ Wih2,   // [G][H]
    const float* __restrict__ Whh2,   // [G][H]
    const float* __restrict__ bih1, const float* __restrict__ bhh1,
    const float* __restrict__ bih2, const float* __restrict__ bhh2,
    const float* __restrict__ Mv,     // [124][32]  (M | v)
    float* __restrict__ h2a)          // [528*64][32]
{
    __shared__ float gA[2][128];      // layer-1 activated gates (double-buffered)
    __shared__ float g2[2][128];      // layer-2 activated gates (double-buffered)
    const int L  = threadIdx.x;       // 0..127
    const int bb = blockIdx.x;
    const int j  = L & 63;            // in-wave lane
    const int gc = (L < GG_) ? L : (GG_ - 1);   // clamped gate id for safe loads
    const bool isg = (gc >= 62 && gc < 93);     // tanh gate?
    const bool selhi = (j >= 32);               // h1-owner half of the wave
    const int sidx = selhi ? (j - 32) : j;      // state index this lane owns

    // recurrent weights as NAMED scalars: row gc of each [124][31] matrix
#define WLOAD(k) float w1_##k  = Whh1[gc * 31 + k]; \
                 float wi2_##k = Wih2[gc * 31 + k]; \
                 float wh2_##k = Whh2[gc * 31 + k];
    REP31(WLOAD)
#undef WLOAD
#define WPIN(k) asm("" : "+v"(w1_##k), "+v"(wi2_##k), "+v"(wh2_##k));
    REP31(WPIN)
#undef WPIN

    const float b2c = bih2[gc] + bhh2[gc];

    // unified state: lanes 0..30 hold (cv2,hv2)[j]; lanes 32..62 hold (cv1,hv1)[j-32]
    float hv = 0.0f, cv = 0.0f;

    // ---- prologue: layer-1 gates for t=0 (h1(-1)=0 -> dot contributes zeros) ----
    float cur0 = pre1[(size_t)bb * 128 + L];
    float pnxt = pre1[((size_t)1 * 64 + bb) * 128 + L];   // p(1)
    float pnx2 = pre1[((size_t)2 * 64 + bb) * 128 + L];   // p(2)
    {
        float pa0 = cur0, pa1 = 0.0f;
#define DPE(k) { float hk = rdlane(hv, 32 + k); pa0 += w1_##k * hk; }
#define DPO(k) { float hk = rdlane(hv, 32 + k); pa1 += w1_##k * hk; }
        REP16E(DPE)
        REP15O(DPO)
#undef DPE
#undef DPO
        float a = pa0 + pa1;
        float z = isg ? (2.0f * a) : a;
        float s = 1.0f / (1.0f + __expf(-z));
        gA[1][L] = isg ? (2.0f * s - 1.0f) : s;
    }
    __syncthreads();
    {
        // h1-owners (lanes 32..62) take h1(0); h2-owners stay at 0
        const float* gsrc = &gA[1][0];
        float ig = gsrc[sidx];
        float fg = gsrc[sidx + 31];
        float gg = gsrc[sidx + 62];
        float og = gsrc[sidx + 93];
        float cvn = fg * cv + ig * gg;
        float e = __expf(-2.0f * cvn);
        float hvn = og * (2.0f / (1.0f + e) - 1.0f);
        cv = selhi ? cvn : 0.0f;
        hv = selhi ? hvn : 0.0f;
    }

    // ---- main merged loop: iteration t computes L2(t) + L1(t+1), t = 0..510 ----
    for (int t = 0; t < TT_ - 1; t++) {
        const int pb = t & 1;
        const float cur = pnxt;          // p(t+1)
        pnxt = pnx2;
        if (t + 3 < TT_) pnx2 = pre1[((size_t)(t + 3) * 64 + bb) * 128 + L];

        // split-chain dots: h1k = rdlane(hv,32+k), h2k = rdlane(hv,k)
        float bi0 = b2c, bi1 = 0.0f, bh0 = 0.0f, bh1 = 0.0f;
        float pa0 = cur, pa1 = 0.0f;
#define DME(k) { float h1k = rdlane(hv, 32 + k); float h2k = rdlane(hv, k); \
                 bi0 += wi2_##k * h1k; bh0 += wh2_##k * h2k; pa0 += w1_##k * h1k; }
#define DMO(k) { float h1k = rdlane(hv, 32 + k); float h2k = rdlane(hv, k); \
                 bi1 += wi2_##k * h1k; bh1 += wh2_##k * h2k; pa1 += w1_##k * h1k; }
        REP16E(DME)
        REP15O(DMO)
#undef DME
#undef DMO
        float b = (bi0 + bi1) + (bh0 + bh1);
        float a = pa0 + pa1;
        {
            float z = isg ? (2.0f * b) : b;
            float s = 1.0f / (1.0f + __expf(-z));
            g2[pb][L] = isg ? (2.0f * s - 1.0f) : s;
        }
        {
            float z = isg ? (2.0f * a) : a;
            float s = 1.0f / (1.0f + __expf(-z));
            gA[pb][L] = isg ? (2.0f * s - 1.0f) : s;
        }
        __syncthreads();
        {
            // unified branchless state update: h2-owners read g2 (L2 gates of t),
            // h1-owners read gA (L1 gates of t+1). Lanes 31/63 compute harmless
            // garbage (reads stay in-bounds, nothing reads their hv).
            const float* gsrc = selhi ? &gA[pb][0] : &g2[pb][0];
            float ig = gsrc[sidx];
            float fg = gsrc[sidx + 31];
            float gg = gsrc[sidx + 62];
            float og = gsrc[sidx + 93];
            cv = fg * cv + ig * gg;
            float e = __expf(-2.0f * cv);
            hv = og * (2.0f / (1.0f + e) - 1.0f);
        }
        if (L < HH_) h2a[((size_t)t * 64 + bb) * 32 + L] = hv;   // h2(t)
    }

    // ---- tail: L2(511) only ----
    {
        float bi0 = b2c, bi1 = 0.0f, bh0 = 0.0f, bh1 = 0.0f;
#define DTE(k) { float h1k = rdlane(hv, 32 + k); float h2k = rdlane(hv, k); \
                 bi0 += wi2_##k * h1k; bh0 += wh2_##k * h2k; }
#define DTO(k) { float h1k = rdlane(hv, 32 + k); float h2k = rdlane(hv, k); \
                 bi1 += wi2_##k * h1k; bh1 += wh2_##k * h2k; }
        REP16E(DTE)
        REP15O(DTO)
#undef DTE
#undef DTO
        float b = (bi0 + bi1) + (bh0 + bh1);
        float z = isg ? (2.0f * b) : b;
        float s = 1.0f / (1.0f + __expf(-z));
        g2[1][L] = isg ? (2.0f * s - 1.0f) : s;
    }
    __syncthreads();
    {
        const float* gsrc = &g2[1][0];
        float ig = gsrc[sidx];
        float fg = gsrc[sidx + 31];
        float gg = gsrc[sidx + 62];
        float og = gsrc[sidx + 93];
        float cvn = fg * cv + ig * gg;
        float e = __expf(-2.0f * cvn);
        float hvn = og * (2.0f / (1.0f + e) - 1.0f);
        cv = selhi ? cv : cvn;          // only h2-owners update
        hv = selhi ? hv : hvn;
    }
    if (L < HH_) h2a[((size_t)(TT_ - 1) * 64 + bb) * 32 + L] = hv;   // h2(511)

    // ---- autoregressive future: pregate = M*h2 + v + b1 (1024-dot eliminated) ----
#define MLOAD(k) float m_##k = Mv[gc * 32 + k];
    REP31(MLOAD)
#undef MLOAD
    float m_31 = Mv[gc * 32 + 31];
#define MPIN(k) asm("" : "+v"(m_##k));
    REP31(MPIN)
#undef MPIN
    asm("" : "+v"(m_31));
    const float b1c = bih1[gc] + bhh1[gc];

    for (int sft = 0; sft < FUT_; sft++) {
        // phase A: L1 pregate  a = b1c + v + M*h2 + Whh1*h1
        float pa0 = b1c + m_31, pa1 = 0.0f;
#define DFE(k) { float h2k = rdlane(hv, k); pa0 += m_##k * h2k; }
#define DFO(k) { float h2k = rdlane(hv, k); pa1 += m_##k * h2k; }
        REP16E(DFE)
        REP15O(DFO)
#undef DFE
#undef DFO
#define DGE(k) { float h1k = rdlane(hv, 32 + k); pa0 += w1_##k * h1k; }
#define DGO(k) { float h1k = rdlane(hv, 32 + k); pa1 += w1_##k * h1k; }
        REP16E(DGE)
        REP15O(DGO)
#undef DGE
#undef DGO
        {
            float a = pa0 + pa1;
            float z = isg ? (2.0f * a) : a;
            float s = 1.0f / (1.0f + __expf(-z));
            gA[0][L] = isg ? (2.0f * s - 1.0f) : s;
        }
        __syncthreads();
        {
            const float* gsrc = &gA[0][0];
            float ig = gsrc[sidx];
            float fg = gsrc[sidx + 31];
            float gg = gsrc[sidx + 62];
            float og = gsrc[sidx + 93];
            float cvn = fg * cv + ig * gg;
            float e = __expf(-2.0f * cvn);
            float hvn = og * (2.0f / (1.0f + e) - 1.0f);
            cv = selhi ? cvn : cv;      // only h1-owners update
            hv = selhi ? hvn : hv;
        }
        // phase B: L2 gates
        float bi0 = b2c, bi1 = 0.0f, bh0 = 0.0f, bh1 = 0.0f;
#define DHE(k) { float h1k = rdlane(hv, 32 + k); float h2k = rdlane(hv, k); \
                 bi0 += wi2_##k * h1k; bh0 += wh2_##k * h2k; }
#define DHO(k) { float h1k = rdlane(hv, 32 + k); float h2k = rdlane(hv, k); \
                 bi1 += wi2_##k * h1k; bh1 += wh2_##k * h2k; }
        REP16E(DHE)
        REP15O(DHO)
#undef DHE
#undef DHO
        {
            float b = (bi0 + bi1) + (bh0 + bh1);
            float z = isg ? (2.0f * b) : b;
            float s = 1.0f / (1.0f + __expf(-z));
            g2[0][L] = isg ? (2.0f * s - 1.0f) : s;
        }
        __syncthreads();
        {
            const float* gsrc = &g2[0][0];
            float ig = gsrc[sidx];
            float fg = gsrc[sidx + 31];
            float gg = gsrc[sidx + 62];
            float og = gsrc[sidx + 93];
            float cvn = fg * cv + ig * gg;
            float e = __expf(-2.0f * cvn);
            float hvn = og * (2.0f / (1.0f + e) - 1.0f);
            cv = selhi ? cv : cvn;      // only h2-owners update
            hv = selhi ? hv : hvn;
        }
        if (L < HH_) h2a[((size_t)(TT_ + sft) * 64 + bb) * 32 + L] = hv;
    }
}

// ---------------- K3: output linear for ALL 528 steps: out[b][t][:] = h2 . WT + b ----------------
__global__ __launch_bounds__(256) void k3_outlin(
    const float* __restrict__ h2a,   // [528*64][32]
    const float* __restrict__ WT,    // [31][1024]
    const float* __restrict__ blin,  // [1024]
    float* __restrict__ out)         // [B][528][1024] fp32
{
    __shared__ __align__(16) float hl[16][32];
    const int tid = threadIdx.x;
    const int m0  = blockIdx.x * 16;
#pragma unroll
    for (int p = 0; p < 2; p++) {
        int i = tid + p * 256;
        int r = i >> 5, k = i & 31;
        hl[r][k] = h2a[(size_t)(m0 + r) * 32 + k];
    }
    __syncthreads();
    const int c0 = tid * 4;
    float4 bl = *(const float4*)(blin + c0);
    float4 acc[16];
#pragma unroll
    for (int r = 0; r < 16; r++) acc[r] = bl;
    for (int k = 0; k < 31; k++) {
        float4 wv = *(const float4*)(WT + k * 1024 + c0);
#pragma unroll
        for (int r = 0; r < 16; r++) {
            float h = hl[r][k];
            acc[r].x += h * wv.x; acc[r].y += h * wv.y;
            acc[r].z += h * wv.z; acc[r].w += h * wv.w;
        }
    }
    const int t  = m0 >> 6;
    const int b0 = m0 & 63;
#pragma unroll
    for (int r = 0; r < 16; r++) {
        int b = b0 + r;
        *(float4*)(out + (size_t)b * OUT_ROW_ + (size_t)t * FF_ + c0) = acc[r];
    }
}

extern "C" void kernel_launch(void* const* d_in, const int* in_sizes, int n_in,
                              void* d_out, int out_size, void* d_ws, size_t ws_size,
                              hipStream_t stream) {
    (void)in_sizes; (void)n_in; (void)out_size; (void)ws_size;
    const float* X    = (const float*)d_in[0];
    const float* Wih1 = (const float*)d_in[1];
    const float* Whh1 = (const float*)d_in[2];
    const float* bih1 = (const float*)d_in[3];
    const float* bhh1 = (const float*)d_in[4];
    const float* Wih2 = (const float*)d_in[5];
    const float* Whh2 = (const float*)d_in[6];
    const float* bih2 = (const float*)d_in[7];
    const float* bhh2 = (const float*)d_in[8];
    const float* Wlin = (const float*)d_in[9];
    const float* blin = (const float*)d_in[10];
    // d_in[11] = future = 16 (constant for this problem)

    float* ws   = (float*)d_ws;
    float* pre1 = ws + PRE1_OFF;
    float* h2a  = ws + H2A_OFF;
    float* WT   = ws + WT_OFF;
    float* Mv   = ws + MV_OFF;
    float* out  = (float*)d_out;

    hipLaunchKernelGGL(k0_prep,    dim3(124),  dim3(256), 0, stream, Wlin, WT);
    hipLaunchKernelGGL(k0b_mv,     dim3(62),   dim3(64),  0, stream, Wih1, Wlin, blin, Mv);
    hipLaunchKernelGGL(k1_pregate, dim3(TT_),  dim3(256), 0, stream, X, Wih1, bih1, bhh1, pre1);
    hipLaunchKernelGGL(k2_recur,   dim3(BB_),  dim3(128), 0, stream, pre1, Whh1, Wih2, Whh2,
                       bih1, bhh1, bih2, bhh2, Mv, h2a);
    hipLaunchKernelGGL(k3_outlin,  dim3(TTOT_*4), dim3(256), 0, stream, h2a, WT, blin, out);
}